// Round 6
// baseline (12175.291 us; speedup 1.0000x reference)
//
#include <hip/hip_runtime.h>
#include <cstdint>
#include <cstddef>

// ---------------------------------------------------------------------------
// MDHP-LSTM on MI355X.  S=512, B=128, D=256, H=512.
// Round-8: sentinel-byte handshake, hardened.
//   * r5 crash fix: poll asm outputs are EARLY-CLOBBER ("=&v") so they can
//     never alias the 64-bit address operand (r5's likely abort cause).
//   * Poll = one 32-byte uniform-address sc0 read per wave per attempt
//     (~500x less L2 poll traffic than r4's data-poll). h loaded ONCE, plain.
//   * GT scratch eliminated: W/U converted fp32->bf16 during LDS staging.
//     ws total 101.1 MB (3 MB slack under proven 104.2 MB ceiling).
//   * Deadlock-proof: 50k failed polls -> sticky escape to r0-proven agent
//     cnt2 flag wait. Producers always fire-and-forget one agent inc/WG/step
//     (off critical path). !xloc chains run the r0 protocol from the start
//     (agent h stores + cnt2 waits + plain h loads).
//   * Proven-kept: parity-dbuf gbuf + ONE barrier/step (r4), per-wave
//     vmcnt(0)->LDS wave-count->last-wave publish (r3/r4), registers for
//     c/mdhp/bias, split h-MFMA accumulators, XCD detection (r2-r4).
// ---------------------------------------------------------------------------

typedef __attribute__((ext_vector_type(8))) short short8;
typedef __attribute__((ext_vector_type(4))) float floatx4;
typedef __attribute__((ext_vector_type(4))) unsigned uintx4;

#define SEQ 512
#define BATCH 128
#define DIN 256
#define HID 512
#define KTOT 768
#define NCHAIN 8
#define NCOLW 32
#define BS_STRIDE 776         // shorts per LDS B-row (768 + 8 pad, 16B aligned)

__device__ __forceinline__ short f2bf(float f) {
  union { float f; unsigned u; } v; v.f = f;
  unsigned u = v.u + 0x7fffu + ((v.u >> 16) & 1u);   // RNE
  return (short)(u >> 16);
}
__device__ __forceinline__ float fsig(float x) {
  return 1.f / (1.f + __expf(-x));
}
__device__ __forceinline__ float ftanh(float x) {
  float a = fabsf(x);
  float e = __expf(-2.f * a);
  float r = (1.f - e) / (1.f + e);
  return copysignf(r, x);
}

// ---- prep: x -> bf16 (4 elems/thread)
__global__ void prep_xb(const float* __restrict__ x, short* __restrict__ xb) {
  int idx = blockIdx.x * 256 + threadIdx.x;           // 4,194,304
  float4 v = ((const float4*)x)[idx];
  short4 o; o.x = f2bf(v.x); o.y = f2bf(v.y); o.z = f2bf(v.z); o.w = f2bf(v.w);
  ((short4*)xb)[idx] = o;
}

// ---- prep: h0 -> hbuf slot 0 (bf16)
__global__ void prep_h0(const float* __restrict__ h0, short* __restrict__ hbuf) {
  int idx = blockIdx.x * 256 + threadIdx.x;           // 65536
  hbuf[idx] = f2bf(h0[idx]);
}

// ---- prep: mdhp[b][h] = tanh(alpha@A - (beta*tspan)@B + theta@C)  (fp32)
__global__ void prep_mdhp(const float* __restrict__ alpha, const float* __restrict__ beta,
                          const float* __restrict__ theta, const float* __restrict__ tspan,
                          const float* __restrict__ A, const float* __restrict__ Bm,
                          const float* __restrict__ C, float* __restrict__ mdhp) {
  int idx = blockIdx.x * 256 + threadIdx.x;           // 65536
  int b = idx >> 9, h = idx & 511;
  float ts = tspan[b];
  float acc = 0.f;
  for (int k = 0; k < 256; ++k)
    acc += alpha[b * 256 + k] * A[k * HID + h] - ts * beta[b * 256 + k] * Bm[k * HID + h];
  for (int k = 0; k < 16; ++k)
    acc += theta[b * 16 + k] * C[k * HID + h];
  mdhp[idx] = tanhf(acc);
}

// ---- zero sync state (must run every launch: graph replays)
__global__ void zero_sync(unsigned* __restrict__ sent32, int* __restrict__ cnt2,
                          unsigned* __restrict__ det) {
  int idx = blockIdx.x * 256 + threadIdx.x;           // grid 128*256 = 32768
  if (idx < 32768) sent32[idx] = 0;                   // 131,072 B of sentinels
  if (idx < NCHAIN * SEQ) cnt2[idx] = 0;
  if (idx < 264) det[idx] = 0;
}

// ---- the persistent recurrence kernel --------------------------------------
__global__ __launch_bounds__(256, 1) void lstm_persist(
    const short* __restrict__ xb, const float* __restrict__ c0,
    const float* __restrict__ bi, const float* __restrict__ bf_,
    const float* __restrict__ bc, const float* __restrict__ bo,
    const float* __restrict__ Wi, const float* __restrict__ Ui,
    const float* __restrict__ Wf, const float* __restrict__ Uf,
    const float* __restrict__ Wc, const float* __restrict__ Uc,
    const float* __restrict__ Wo, const float* __restrict__ Uo,
    const float* __restrict__ mdhp,
    unsigned* det, unsigned char* sent, int* cnt2, short* hbuf, float* out) {
  __shared__ __align__(16) short Bs[64 * BS_STRIDE];   // 99,328 B
  __shared__ float gbuf[2][4][16][17];                 // parity dbuf: 8,704 B
  __shared__ int wv[SEQ];                              // per-step wave counter
  __shared__ int s_mode;

  const int tid = threadIdx.x;
  const int wg = blockIdx.x;
  const int chain = wg & 7;        // XCD-local under round-robin wg->XCD
  const int j = wg >> 3;           // 0..31 column group

  // stage B^T slice straight from fp32 W/U (no GT scratch): row lr = g*16+c
  // holds bf16 of (k<256 ? W_g[k][hc] : U_g[k-256][hc]), hc = j*16+c.
  for (int g = 0; g < 4; ++g) {
    const float* W = (g == 0) ? Wi : (g == 1) ? Wf : (g == 2) ? Wc : Wo;
    const float* U = (g == 0) ? Ui : (g == 1) ? Uf : (g == 2) ? Uc : Uo;
    for (int it = tid; it < 16 * KTOT; it += 256) {
      int c = it & 15;                      // lane-consecutive -> coalesced hc
      int k = it >> 4;
      int hc = (j << 4) + c;
      float v = (k < DIN) ? W[k * HID + hc] : U[(k - DIN) * HID + hc];
      Bs[(g * 16 + c) * BS_STRIDE + k] = f2bf(v);
    }
  }
  for (int i = tid; i < SEQ; i += 256) wv[i] = 0;

  // per-thread epilogue state in registers
  const int er = tid >> 4, ec = tid & 15;
  const int brow = (chain << 4) + er, hcol = (j << 4) + ec;
  float creg = c0[brow * HID + hcol];
  const float mdv = mdhp[brow * HID + hcol];
  const float b0 = bi[hcol], b1 = bf_[hcol], b2 = bc[hcol], b3 = bo[hcol];

  // ---- XCD homogeneity detection (agent-scope; one-time; r2-r4 proven) -----
  unsigned xid;
  asm volatile("s_getreg_b32 %0, hwreg(HW_REG_XCC_ID)" : "=s"(xid));
  xid &= 15u;
  if (tid == 0) {
    __hip_atomic_store(&det[wg], xid, __ATOMIC_RELAXED, __HIP_MEMORY_SCOPE_AGENT);
    __hip_atomic_fetch_add((int*)&det[256 + chain], 1, __ATOMIC_RELEASE,
                           __HIP_MEMORY_SCOPE_AGENT);
    while (__hip_atomic_load((int*)&det[256 + chain], __ATOMIC_ACQUIRE,
                             __HIP_MEMORY_SCOPE_AGENT) < NCOLW)
      __builtin_amdgcn_s_sleep(2);
    unsigned x0 = __hip_atomic_load(&det[chain], __ATOMIC_RELAXED,
                                    __HIP_MEMORY_SCOPE_AGENT);
    int ok = 1;
    for (int jj = 1; jj < NCOLW; ++jj)
      ok &= (__hip_atomic_load(&det[chain + 8 * jj], __ATOMIC_RELAXED,
                               __HIP_MEMORY_SCOPE_AGENT) == x0);
    s_mode = ok;
  }
  __syncthreads();                            // also covers Bs / wv staging
  const bool xloc = (s_mode != 0);

  const int lane = tid & 63;
  const int g = tid >> 6;                 // wave = gate
  const int mr = lane & 15;               // A-row / B-col within tile
  const int q = lane >> 4;                // quad
  const int bglob = (chain << 4) + mr;
  const short* Brow = &Bs[(g * 16 + mr) * BS_STRIDE + q * 8];
  int* mycnt2 = cnt2 + chain * SEQ;
  bool esc = !xloc;                       // sticky: agent-flag waiting mode

  for (int t = 0; t < SEQ; ++t) {
    // ---- issue x A-frag loads (h-independent; in flight across the poll)
    const short* xr = xb + ((size_t)t * BATCH + bglob) * DIN + q * 8;
    short8 xaf[8];
#pragma unroll
    for (int kk = 0; kk < 8; ++kk) xaf[kk] = *(const short8*)(xr + kk * 32);

    // ---- wait for h_{t-1}: 32-byte sentinel, sc0 (L2) reads ---------------
    if (t > 0) {
      if (!esc) {
        const unsigned long long spa = (unsigned long long)(uintptr_t)
            ((const char*)sent + ((size_t)(chain * SEQ + t) << 5));
        int att = 0;
        for (;;) {
          uintx4 s0, s1;
          asm volatile("global_load_dwordx4 %0, %2, off sc0\n\t"
                       "global_load_dwordx4 %1, %2, off offset:16 sc0\n\t"
                       "s_waitcnt vmcnt(0)"
                       : "=&v"(s0), "=&v"(s1)     // early-clobber: no aliasing
                       : "v"(spa)
                       : "memory");
          unsigned m = s0.x & s0.y & s0.z & s0.w & s1.x & s1.y & s1.z & s1.w;
          if (m == 0x01010101u) break;
          if (att > 200) __builtin_amdgcn_s_sleep(1);
          if (++att > 50000) { esc = true; break; }   // bounded; sticky
        }
      }
      if (esc) {
        while (__hip_atomic_load(&mycnt2[t - 1], __ATOMIC_RELAXED,
                                 __HIP_MEMORY_SCOPE_AGENT) < NCOLW)
          __builtin_amdgcn_s_sleep(1);
      }
      __builtin_amdgcn_sched_barrier(0);
    }

    // ---- h A-frag loads, ONCE, plain (L1-cold fresh addr; L2 serves dirty)
    const short* hr = hbuf + ((size_t)t * BATCH + bglob) * HID + q * 8;
    short8 haf[16];
#pragma unroll
    for (int kk = 0; kk < 16; ++kk) haf[kk] = *(const short8*)(hr + kk * 32);

    floatx4 ax  = {0.f, 0.f, 0.f, 0.f};
    floatx4 ah0 = {0.f, 0.f, 0.f, 0.f};
    floatx4 ah1 = {0.f, 0.f, 0.f, 0.f};

    // ---- x @ W MFMAs (overlap h-load latency)
#pragma unroll
    for (int kk = 0; kk < 8; ++kk)
      ax = __builtin_amdgcn_mfma_f32_16x16x32_bf16(
          xaf[kk], *(const short8*)(Brow + kk * 32), ax, 0, 0, 0);

    // ---- h @ U MFMAs, two independent chains for latency
#pragma unroll
    for (int kk = 0; kk < 8; ++kk) {
      ah0 = __builtin_amdgcn_mfma_f32_16x16x32_bf16(
          haf[kk], *(const short8*)(Brow + DIN + kk * 32), ah0, 0, 0, 0);
      ah1 = __builtin_amdgcn_mfma_f32_16x16x32_bf16(
          haf[8 + kk], *(const short8*)(Brow + DIN + (8 + kk) * 32), ah1, 0, 0, 0);
    }

    // ---- epilogue: C/D layout col=lane&15, row=q*4+i (m89); gbuf parity
    const int p = t & 1;
#pragma unroll
    for (int i = 0; i < 4; ++i)
      gbuf[p][g][q * 4 + i][mr] = ax[i] + ah0[i] + ah1[i];
    __syncthreads();                         // the ONE barrier per step
    {
      float gi = gbuf[p][0][er][ec] + b0;
      float gf = gbuf[p][1][er][ec] + b1;
      float gc = gbuf[p][2][er][ec] + b2;
      float go = gbuf[p][3][er][ec] + b3;
      float it = fsig(gi), ft = fsig(gf), ot = fsig(go);
      float ch = ftanh(gc);
      float cn = mdv * (ft * creg + it * ch);
      creg = cn;
      float hv = ot * ftanh(cn);

      if (t < SEQ - 1) {
        // bf16 h store to slot t+1: pair lanes -> one 4B word
        unsigned hb = (unsigned)(unsigned short)f2bf(hv);
        unsigned other = (unsigned)__shfl_xor((int)hb, 1, 64);
        if ((tid & 1) == 0) {
          unsigned pack = hb | (other << 16);
          size_t hidx = ((size_t)(t + 1) * BATCH + brow) * HID + hcol; // ec even
          if (xloc)
            *(unsigned*)&hbuf[hidx] = pack;     // plain -> shared XCD L2
          else
            __hip_atomic_store((unsigned*)&hbuf[hidx], pack, __ATOMIC_RELAXED,
                               __HIP_MEMORY_SCOPE_AGENT);
        }
        // publish: this wave's h acked -> LDS count -> last wave signals
        asm volatile("s_waitcnt vmcnt(0)" ::: "memory");
        if (lane == 0) {
          int old = __hip_atomic_fetch_add(&wv[t], 1, __ATOMIC_RELAXED,
                                           __HIP_MEMORY_SCOPE_WORKGROUP);
          if (old == 3) {                       // last wave of this WG
            if (xloc) {
              volatile unsigned char* sb = (volatile unsigned char*)sent +
                  ((size_t)(chain * SEQ + t + 1) << 5) + j;
              *sb = 1;                          // plain byte -> XCD L2
            }
            __hip_atomic_fetch_add(&mycnt2[t], 1, __ATOMIC_RELAXED,
                                   __HIP_MEMORY_SCOPE_AGENT);  // insurance
          }
        }
      }

      // fp32 output (not read by consumers) after the publish
      size_t oidx = ((size_t)t * BATCH + brow) * HID + hcol;
      out[oidx] = hv;
      if (t == SEQ - 1) {
        size_t base = (size_t)SEQ * BATCH * HID;
        int e = brow * HID + hcol;
        out[base + e] = hv;                    // h_T
        out[base + BATCH * HID + e] = cn;      // c_T
      }
    }
  }
}

// ---------------------------------------------------------------------------
extern "C" void kernel_launch(void* const* d_in, const int* in_sizes, int n_in,
                              void* d_out, int out_size, void* d_ws, size_t ws_size,
                              hipStream_t stream) {
  const float* x     = (const float*)d_in[0];
  const float* h0    = (const float*)d_in[1];
  const float* c0    = (const float*)d_in[2];
  const float* alpha = (const float*)d_in[3];
  const float* beta  = (const float*)d_in[4];
  const float* theta = (const float*)d_in[5];
  const float* tspan = (const float*)d_in[6];
  const float* Amd   = (const float*)d_in[7];
  const float* Bmd   = (const float*)d_in[8];
  const float* Cmd   = (const float*)d_in[9];
  const float* Wi = (const float*)d_in[10]; const float* Ui = (const float*)d_in[11];
  const float* bi = (const float*)d_in[12];
  const float* Wf = (const float*)d_in[13]; const float* Uf = (const float*)d_in[14];
  const float* bf_ = (const float*)d_in[15];
  const float* Wc = (const float*)d_in[16]; const float* Uc = (const float*)d_in[17];
  const float* bc = (const float*)d_in[18];
  const float* Wo = (const float*)d_in[19]; const float* Uo = (const float*)d_in[20];
  const float* bo = (const float*)d_in[21];

  float* out = (float*)d_out;
  char* ws = (char*)d_ws;
  // ws layout (bytes):
  float* mdhp        = (float*)ws;                    // @0              262,144
  int*   cnt2        = (int*)(ws + 262144);           // @262,144         16,384
  unsigned* det      = (unsigned*)(ws + 278528);      // @278,528          4,096
  unsigned char* sent= (unsigned char*)(ws + 282624); // @282,624        131,072
  short* xb          = (short*)(ws + 413696);         // @413,696     33,554,432
  short* hbuf        = (short*)(ws + 33968128);       // @33,968,128  67,108,864
  // total: 101,076,992 B  (3.1 MB under the proven 104,218,624 ceiling)

  zero_sync<<<128, 256, 0, stream>>>((unsigned*)sent, cnt2, det);
  prep_xb<<<16384, 256, 0, stream>>>(x, xb);
  prep_h0<<<256, 256, 0, stream>>>(h0, hbuf);
  prep_mdhp<<<256, 256, 0, stream>>>(alpha, beta, theta, tspan, Amd, Bmd, Cmd, mdhp);
  lstm_persist<<<NCHAIN * NCOLW, 256, 0, stream>>>(
      xb, c0, bi, bf_, bc, bo, Wi, Ui, Wf, Uf, Wc, Uc, Wo, Uo,
      mdhp, det, sent, cnt2, hbuf, out);
}

// Round 7
// 6846.281 us; speedup vs baseline: 1.7784x; 1.7784x over previous
//
#include <hip/hip_runtime.h>
#include <cstdint>
#include <cstddef>

// ---------------------------------------------------------------------------
// MDHP-LSTM on MI355X.  S=512, B=128, D=256, H=512.
// Round-9: r6 sentinel structure on r0-proven AGENT transport.
// Evidence:
//   * r4/r6: same-address re-polling with plain/sc0 loads reads STALE L1
//     until capacity eviction -> sc0 does not reliably bypass L1. All
//     same-address polls must use agent atomic loads (IF-coherent, r0-proven
//     live across full runs).
//   * r0's 4us/step decomposes into: 32 same-address agent RMW incs
//     (serialized, ~2-3k cy) + tid0-poll->LDS-fanout + double agent h round
//     trips. Fix kept from r6: per-WG sentinel BYTES (parallel at IF),
//     batched 4x8B agent-load poll by every wave, no RMW, no fanout.
//   * h channel (r0/r2/r3/r6-proven): plain stores -> XCD L2; fresh-address
//     plain loads (L1 miss by construction; 4 waves/CU share the L1 fill).
//   * ACQUIRE on the final poll load orders the h loads (no fence builtin;
//     backend emits waitcnt+inv; dirty L2 lines survive inv).
//   * No escape hatch: transport is r0's (never deadlocked, never stale).
// ---------------------------------------------------------------------------

typedef __attribute__((ext_vector_type(8))) short short8;
typedef __attribute__((ext_vector_type(4))) float floatx4;

#define SEQ 512
#define BATCH 128
#define DIN 256
#define HID 512
#define KTOT 768
#define NCHAIN 8
#define NCOLW 32
#define BS_STRIDE 776         // shorts per LDS B-row (768 + 8 pad, 16B aligned)

__device__ __forceinline__ short f2bf(float f) {
  union { float f; unsigned u; } v; v.f = f;
  unsigned u = v.u + 0x7fffu + ((v.u >> 16) & 1u);   // RNE
  return (short)(u >> 16);
}
__device__ __forceinline__ float fsig(float x) {
  return 1.f / (1.f + __expf(-x));
}
__device__ __forceinline__ float ftanh(float x) {
  float a = fabsf(x);
  float e = __expf(-2.f * a);
  float r = (1.f - e) / (1.f + e);
  return copysignf(r, x);
}

// ---- prep: x -> bf16 (4 elems/thread)
__global__ void prep_xb(const float* __restrict__ x, short* __restrict__ xb) {
  int idx = blockIdx.x * 256 + threadIdx.x;           // 4,194,304
  float4 v = ((const float4*)x)[idx];
  short4 o; o.x = f2bf(v.x); o.y = f2bf(v.y); o.z = f2bf(v.z); o.w = f2bf(v.w);
  ((short4*)xb)[idx] = o;
}

// ---- prep: h0 -> hbuf slot 0 (bf16)
__global__ void prep_h0(const float* __restrict__ h0, short* __restrict__ hbuf) {
  int idx = blockIdx.x * 256 + threadIdx.x;           // 65536
  hbuf[idx] = f2bf(h0[idx]);
}

// ---- prep: mdhp[b][h] = tanh(alpha@A - (beta*tspan)@B + theta@C)  (fp32)
__global__ void prep_mdhp(const float* __restrict__ alpha, const float* __restrict__ beta,
                          const float* __restrict__ theta, const float* __restrict__ tspan,
                          const float* __restrict__ A, const float* __restrict__ Bm,
                          const float* __restrict__ C, float* __restrict__ mdhp) {
  int idx = blockIdx.x * 256 + threadIdx.x;           // 65536
  int b = idx >> 9, h = idx & 511;
  float ts = tspan[b];
  float acc = 0.f;
  for (int k = 0; k < 256; ++k)
    acc += alpha[b * 256 + k] * A[k * HID + h] - ts * beta[b * 256 + k] * Bm[k * HID + h];
  for (int k = 0; k < 16; ++k)
    acc += theta[b * 16 + k] * C[k * HID + h];
  mdhp[idx] = tanhf(acc);
}

// ---- zero sync state (must run every launch: graph replays)
__global__ void zero_sync(unsigned* __restrict__ sent32, unsigned* __restrict__ det) {
  int idx = blockIdx.x * 256 + threadIdx.x;           // grid 128*256 = 32768
  if (idx < 32768) sent32[idx] = 0;                   // 131,072 B of sentinels
  if (idx < 264) det[idx] = 0;
}

// ---- the persistent recurrence kernel --------------------------------------
__global__ __launch_bounds__(256, 1) void lstm_persist(
    const short* __restrict__ xb, const float* __restrict__ c0,
    const float* __restrict__ bi, const float* __restrict__ bf_,
    const float* __restrict__ bc, const float* __restrict__ bo,
    const float* __restrict__ Wi, const float* __restrict__ Ui,
    const float* __restrict__ Wf, const float* __restrict__ Uf,
    const float* __restrict__ Wc, const float* __restrict__ Uc,
    const float* __restrict__ Wo, const float* __restrict__ Uo,
    const float* __restrict__ mdhp,
    unsigned* det, unsigned char* sent, short* hbuf, float* out) {
  __shared__ __align__(16) short Bs[64 * BS_STRIDE];   // 99,328 B
  __shared__ float gbuf[2][4][16][17];                 // parity dbuf: 8,704 B
  __shared__ int wv[SEQ];                              // per-step wave counter
  __shared__ int s_mode;

  const int tid = threadIdx.x;
  const int wg = blockIdx.x;
  const int chain = wg & 7;        // XCD-local under round-robin wg->XCD
  const int j = wg >> 3;           // 0..31 column group

  // stage B^T slice straight from fp32 W/U: row lr = g*16+c holds bf16 of
  // (k<256 ? W_g[k][hc] : U_g[k-256][hc]), hc = j*16+c.  (r6-proven)
  for (int g = 0; g < 4; ++g) {
    const float* W = (g == 0) ? Wi : (g == 1) ? Wf : (g == 2) ? Wc : Wo;
    const float* U = (g == 0) ? Ui : (g == 1) ? Uf : (g == 2) ? Uc : Uo;
    for (int it = tid; it < 16 * KTOT; it += 256) {
      int c = it & 15;                      // lane-consecutive -> coalesced hc
      int k = it >> 4;
      int hc = (j << 4) + c;
      float v = (k < DIN) ? W[k * HID + hc] : U[(k - DIN) * HID + hc];
      Bs[(g * 16 + c) * BS_STRIDE + k] = f2bf(v);
    }
  }
  for (int i = tid; i < SEQ; i += 256) wv[i] = 0;

  // per-thread epilogue state in registers
  const int er = tid >> 4, ec = tid & 15;
  const int brow = (chain << 4) + er, hcol = (j << 4) + ec;
  float creg = c0[brow * HID + hcol];
  const float mdv = mdhp[brow * HID + hcol];
  const float b0 = bi[hcol], b1 = bf_[hcol], b2 = bc[hcol], b3 = bo[hcol];

  // ---- XCD homogeneity detection (agent-scope; one-time; r2-r6 proven) -----
  unsigned xid;
  asm volatile("s_getreg_b32 %0, hwreg(HW_REG_XCC_ID)" : "=s"(xid));
  xid &= 15u;
  if (tid == 0) {
    __hip_atomic_store(&det[wg], xid, __ATOMIC_RELAXED, __HIP_MEMORY_SCOPE_AGENT);
    __hip_atomic_fetch_add((int*)&det[256 + chain], 1, __ATOMIC_RELEASE,
                           __HIP_MEMORY_SCOPE_AGENT);
    while (__hip_atomic_load((int*)&det[256 + chain], __ATOMIC_ACQUIRE,
                             __HIP_MEMORY_SCOPE_AGENT) < NCOLW)
      __builtin_amdgcn_s_sleep(2);
    unsigned x0 = __hip_atomic_load(&det[chain], __ATOMIC_RELAXED,
                                    __HIP_MEMORY_SCOPE_AGENT);
    int ok = 1;
    for (int jj = 1; jj < NCOLW; ++jj)
      ok &= (__hip_atomic_load(&det[chain + 8 * jj], __ATOMIC_RELAXED,
                               __HIP_MEMORY_SCOPE_AGENT) == x0);
    s_mode = ok;
  }
  __syncthreads();                            // also covers Bs / wv staging
  const bool xloc = (s_mode != 0);

  const int lane = tid & 63;
  const int g = tid >> 6;                 // wave = gate
  const int mr = lane & 15;               // A-row / B-col within tile
  const int q = lane >> 4;                // quad
  const int bglob = (chain << 4) + mr;
  const short* Brow = &Bs[(g * 16 + mr) * BS_STRIDE + q * 8];

  for (int t = 0; t < SEQ; ++t) {
    // ---- issue x A-frag loads (h-independent; in flight across the poll)
    const short* xr = xb + ((size_t)t * BATCH + bglob) * DIN + q * 8;
    short8 xaf[8];
#pragma unroll
    for (int kk = 0; kk < 8; ++kk) xaf[kk] = *(const short8*)(xr + kk * 32);

    // ---- wait for h_{t-1}: 32 sentinel bytes via 4x8B AGENT loads ---------
    // (IF-coherent; no L1 staleness possible — r0-proven transport, batched)
    if (t > 0) {
      const unsigned long long* sp = (const unsigned long long*)
          (sent + ((size_t)(chain * SEQ + t) << 5));
      int att = 0;
      for (;;) {
        unsigned long long a = __hip_atomic_load(&sp[0], __ATOMIC_RELAXED,
                                                 __HIP_MEMORY_SCOPE_AGENT);
        unsigned long long b = __hip_atomic_load(&sp[1], __ATOMIC_RELAXED,
                                                 __HIP_MEMORY_SCOPE_AGENT);
        unsigned long long c = __hip_atomic_load(&sp[2], __ATOMIC_RELAXED,
                                                 __HIP_MEMORY_SCOPE_AGENT);
        unsigned long long d = __hip_atomic_load(&sp[3], __ATOMIC_RELAXED,
                                                 __HIP_MEMORY_SCOPE_AGENT);
        if ((a & b & c & d) == 0x0101010101010101ull) break;
        if (++att > 2) __builtin_amdgcn_s_sleep(1);
      }
      // ACQUIRE: orders the h loads below after the sentinel observation
      (void)__hip_atomic_load(&sp[0], __ATOMIC_ACQUIRE, __HIP_MEMORY_SCOPE_AGENT);
      __builtin_amdgcn_sched_barrier(0);
    }

    // ---- h A-frag loads, ONCE, plain (fresh addr -> L1 miss -> XCD L2;
    //      4 waves share the CU's L1 fill).  !xloc: IF-coherent asm loads.
    const short* hr = hbuf + ((size_t)t * BATCH + bglob) * HID + q * 8;
    short8 haf[16];
    if (xloc) {
#pragma unroll
      for (int kk = 0; kk < 16; ++kk) haf[kk] = *(const short8*)(hr + kk * 32);
    } else {
      asm volatile(
          "global_load_dwordx4 %0,  %16, off sc0 sc1\n\t"
          "global_load_dwordx4 %1,  %16, off offset:64 sc0 sc1\n\t"
          "global_load_dwordx4 %2,  %16, off offset:128 sc0 sc1\n\t"
          "global_load_dwordx4 %3,  %16, off offset:192 sc0 sc1\n\t"
          "global_load_dwordx4 %4,  %16, off offset:256 sc0 sc1\n\t"
          "global_load_dwordx4 %5,  %16, off offset:320 sc0 sc1\n\t"
          "global_load_dwordx4 %6,  %16, off offset:384 sc0 sc1\n\t"
          "global_load_dwordx4 %7,  %16, off offset:448 sc0 sc1\n\t"
          "global_load_dwordx4 %8,  %16, off offset:512 sc0 sc1\n\t"
          "global_load_dwordx4 %9,  %16, off offset:576 sc0 sc1\n\t"
          "global_load_dwordx4 %10, %16, off offset:640 sc0 sc1\n\t"
          "global_load_dwordx4 %11, %16, off offset:704 sc0 sc1\n\t"
          "global_load_dwordx4 %12, %16, off offset:768 sc0 sc1\n\t"
          "global_load_dwordx4 %13, %16, off offset:832 sc0 sc1\n\t"
          "global_load_dwordx4 %14, %16, off offset:896 sc0 sc1\n\t"
          "global_load_dwordx4 %15, %16, off offset:960 sc0 sc1\n\t"
          "s_waitcnt vmcnt(0)"
          : "=&v"(haf[0]), "=&v"(haf[1]), "=&v"(haf[2]), "=&v"(haf[3]),
            "=&v"(haf[4]), "=&v"(haf[5]), "=&v"(haf[6]), "=&v"(haf[7]),
            "=&v"(haf[8]), "=&v"(haf[9]), "=&v"(haf[10]), "=&v"(haf[11]),
            "=&v"(haf[12]), "=&v"(haf[13]), "=&v"(haf[14]), "=&v"(haf[15])
          : "v"((unsigned long long)(uintptr_t)hr)
          : "memory");
      __builtin_amdgcn_sched_barrier(0);
    }

    floatx4 ax  = {0.f, 0.f, 0.f, 0.f};
    floatx4 ah0 = {0.f, 0.f, 0.f, 0.f};
    floatx4 ah1 = {0.f, 0.f, 0.f, 0.f};

    // ---- x @ W MFMAs (overlap h-load latency)
#pragma unroll
    for (int kk = 0; kk < 8; ++kk)
      ax = __builtin_amdgcn_mfma_f32_16x16x32_bf16(
          xaf[kk], *(const short8*)(Brow + kk * 32), ax, 0, 0, 0);

    // ---- h @ U MFMAs, two independent chains for latency
#pragma unroll
    for (int kk = 0; kk < 8; ++kk) {
      ah0 = __builtin_amdgcn_mfma_f32_16x16x32_bf16(
          haf[kk], *(const short8*)(Brow + DIN + kk * 32), ah0, 0, 0, 0);
      ah1 = __builtin_amdgcn_mfma_f32_16x16x32_bf16(
          haf[8 + kk], *(const short8*)(Brow + DIN + (8 + kk) * 32), ah1, 0, 0, 0);
    }

    // ---- epilogue: C/D layout col=lane&15, row=q*4+i (m89); gbuf parity
    const int p = t & 1;
#pragma unroll
    for (int i = 0; i < 4; ++i)
      gbuf[p][g][q * 4 + i][mr] = ax[i] + ah0[i] + ah1[i];
    __syncthreads();                         // the ONE barrier per step
    {
      float gi = gbuf[p][0][er][ec] + b0;
      float gf = gbuf[p][1][er][ec] + b1;
      float gc = gbuf[p][2][er][ec] + b2;
      float go = gbuf[p][3][er][ec] + b3;
      float it = fsig(gi), ft = fsig(gf), ot = fsig(go);
      float ch = ftanh(gc);
      float cn = mdv * (ft * creg + it * ch);
      creg = cn;
      float hv = ot * ftanh(cn);

      if (t < SEQ - 1) {
        // bf16 h store to slot t+1: pair lanes -> one 4B word
        unsigned hb = (unsigned)(unsigned short)f2bf(hv);
        unsigned other = (unsigned)__shfl_xor((int)hb, 1, 64);
        if ((tid & 1) == 0) {
          unsigned pack = hb | (other << 16);
          size_t hidx = ((size_t)(t + 1) * BATCH + brow) * HID + hcol; // ec even
          if (xloc)
            *(unsigned*)&hbuf[hidx] = pack;     // plain -> shared XCD L2
          else
            __hip_atomic_store((unsigned*)&hbuf[hidx], pack, __ATOMIC_RELAXED,
                               __HIP_MEMORY_SCOPE_AGENT);
        }
        // publish: this wave's h acked -> LDS count -> last wave's sentinel
        asm volatile("s_waitcnt vmcnt(0)" ::: "memory");
        if (lane == 0) {
          int old = __hip_atomic_fetch_add(&wv[t], 1, __ATOMIC_RELAXED,
                                           __HIP_MEMORY_SCOPE_WORKGROUP);
          if (old == 3) {                       // all 4 waves' h committed
            __hip_atomic_store(
                sent + ((size_t)(chain * SEQ + t + 1) << 5) + j,
                (unsigned char)1, __ATOMIC_RELAXED, __HIP_MEMORY_SCOPE_AGENT);
          }
        }
      }

      // fp32 output (not read by consumers) after the publish
      size_t oidx = ((size_t)t * BATCH + brow) * HID + hcol;
      out[oidx] = hv;
      if (t == SEQ - 1) {
        size_t base = (size_t)SEQ * BATCH * HID;
        int e = brow * HID + hcol;
        out[base + e] = hv;                    // h_T
        out[base + BATCH * HID + e] = cn;      // c_T
      }
    }
  }
}

// ---------------------------------------------------------------------------
extern "C" void kernel_launch(void* const* d_in, const int* in_sizes, int n_in,
                              void* d_out, int out_size, void* d_ws, size_t ws_size,
                              hipStream_t stream) {
  const float* x     = (const float*)d_in[0];
  const float* h0    = (const float*)d_in[1];
  const float* c0    = (const float*)d_in[2];
  const float* alpha = (const float*)d_in[3];
  const float* beta  = (const float*)d_in[4];
  const float* theta = (const float*)d_in[5];
  const float* tspan = (const float*)d_in[6];
  const float* Amd   = (const float*)d_in[7];
  const float* Bmd   = (const float*)d_in[8];
  const float* Cmd   = (const float*)d_in[9];
  const float* Wi = (const float*)d_in[10]; const float* Ui = (const float*)d_in[11];
  const float* bi = (const float*)d_in[12];
  const float* Wf = (const float*)d_in[13]; const float* Uf = (const float*)d_in[14];
  const float* bf_ = (const float*)d_in[15];
  const float* Wc = (const float*)d_in[16]; const float* Uc = (const float*)d_in[17];
  const float* bc = (const float*)d_in[18];
  const float* Wo = (const float*)d_in[19]; const float* Uo = (const float*)d_in[20];
  const float* bo = (const float*)d_in[21];

  float* out = (float*)d_out;
  char* ws = (char*)d_ws;
  // ws layout (bytes) — identical to r6 (passed):
  float* mdhp        = (float*)ws;                    // @0              262,144
  unsigned* det      = (unsigned*)(ws + 278528);      // @278,528          4,096
  unsigned char* sent= (unsigned char*)(ws + 282624); // @282,624        131,072
  short* xb          = (short*)(ws + 413696);         // @413,696     33,554,432
  short* hbuf        = (short*)(ws + 33968128);       // @33,968,128  67,108,864
  // total: 101,076,992 B  (3.1 MB under the proven 104.2 MB ceiling)

  zero_sync<<<128, 256, 0, stream>>>((unsigned*)sent, det);
  prep_xb<<<16384, 256, 0, stream>>>(x, xb);
  prep_h0<<<256, 256, 0, stream>>>(h0, hbuf);
  prep_mdhp<<<256, 256, 0, stream>>>(alpha, beta, theta, tspan, Amd, Bmd, Cmd, mdhp);
  lstm_persist<<<NCHAIN * NCOLW, 256, 0, stream>>>(
      xb, c0, bi, bf_, bc, bo, Wi, Ui, Wf, Uf, Wc, Uc, Wo, Uo,
      mdhp, det, sent, hbuf, out);
}

// Round 8
// 4966.620 us; speedup vs baseline: 2.4514x; 1.3785x over previous
//
#include <hip/hip_runtime.h>
#include <cstdint>
#include <cstddef>

// ---------------------------------------------------------------------------
// MDHP-LSTM on MI355X.  S=512, B=128, D=256, H=512.
// Round-10: FLAGLESS data-as-flag with fence-coherent retry.
// Transport taxonomy (measured r0-r7):
//   * flag protocols: r0/r3 tid0-RMW ~4us/step; load-polled flags ~13us/step
//     (same-line IF contention); 4 serial IF trips is the flag floor.
//   * r4 data-poll failed ONLY on stale-L1 retries (no coherence op).
// This round: producers agent-store h (IF write-through, r0-proven) and
// NOTHING else. Consumers plain-load their h fragments (fresh t-indexed
// address -> L1 cold), verify against the 0xFFFFFFFF prefill sentinel
// (unreachable: |h|<1 -> bf16 halves <= 0xBF7F), and on any NaN word do
// __builtin_amdgcn_fence(ACQUIRE,"agent") -> buffer_inv -> reload reads IF.
// 2 serial IF trips/step instead of 4. No flags, no counters, no publish,
// no XCD detection, ONE barrier/step.
// Liveness: after 64 fenced retries a wave falls back (per step) to
// per-dword agent ATOMIC loads of its tile — bedrock-coherent, bounded.
// ---------------------------------------------------------------------------

typedef __attribute__((ext_vector_type(8))) short short8;
typedef __attribute__((ext_vector_type(4))) float floatx4;

#define SEQ 512
#define BATCH 128
#define DIN 256
#define HID 512
#define KTOT 768
#define NCHAIN 8
#define NCOLW 32
#define BS_STRIDE 776         // shorts per LDS B-row (768 + 8 pad, 16B aligned)

__device__ __forceinline__ short f2bf(float f) {
  union { float f; unsigned u; } v; v.f = f;
  unsigned u = v.u + 0x7fffu + ((v.u >> 16) & 1u);   // RNE
  return (short)(u >> 16);
}
__device__ __forceinline__ float fsig(float x) {
  return 1.f / (1.f + __expf(-x));
}
__device__ __forceinline__ float ftanh(float x) {
  float a = fabsf(x);
  float e = __expf(-2.f * a);
  float r = (1.f - e) / (1.f + e);
  return copysignf(r, x);
}
__device__ __forceinline__ unsigned umax2(unsigned a, unsigned b) {
  return a > b ? a : b;
}
// max over the 64 dwords of a 16-frag tile; == 0xFFFFFFFF iff any word is
// still the prefill sentinel (real bf16 halves are <= 0xBF7F since |h|<1).
__device__ __forceinline__ unsigned nan_max(const short8 (&haf)[16]) {
  unsigned m = 0;
#pragma unroll
  for (int kk = 0; kk < 16; ++kk) {
    unsigned w[4];
    __builtin_memcpy(w, &haf[kk], 16);
    m = umax2(m, umax2(umax2(w[0], w[1]), umax2(w[2], w[3])));
  }
  return m;
}

// ---- prep: x -> bf16 (4 elems/thread)
__global__ void prep_xb(const float* __restrict__ x, short* __restrict__ xb) {
  int idx = blockIdx.x * 256 + threadIdx.x;           // 4,194,304
  float4 v = ((const float4*)x)[idx];
  short4 o; o.x = f2bf(v.x); o.y = f2bf(v.y); o.z = f2bf(v.z); o.w = f2bf(v.w);
  ((short4*)xb)[idx] = o;
}

// ---- prep: fill hbuf with NaN sentinel (16B/thread over 67,108,864 B)
// Must run every launch (graph replay re-poisons the buffer).
__global__ void fill_nan(uint4* __restrict__ hb) {
  int idx = blockIdx.x * 256 + threadIdx.x;           // 4,194,304
  uint4 v; v.x = 0xFFFFFFFFu; v.y = 0xFFFFFFFFu; v.z = 0xFFFFFFFFu; v.w = 0xFFFFFFFFu;
  hb[idx] = v;
}

// ---- prep: h0 -> hbuf slot 0 (bf16); runs AFTER fill_nan (stream order)
__global__ void prep_h0(const float* __restrict__ h0, short* __restrict__ hbuf) {
  int idx = blockIdx.x * 256 + threadIdx.x;           // 65536
  hbuf[idx] = f2bf(h0[idx]);
}

// ---- prep: mdhp[b][h] = tanh(alpha@A - (beta*tspan)@B + theta@C)  (fp32)
__global__ void prep_mdhp(const float* __restrict__ alpha, const float* __restrict__ beta,
                          const float* __restrict__ theta, const float* __restrict__ tspan,
                          const float* __restrict__ A, const float* __restrict__ Bm,
                          const float* __restrict__ C, float* __restrict__ mdhp) {
  int idx = blockIdx.x * 256 + threadIdx.x;           // 65536
  int b = idx >> 9, h = idx & 511;
  float ts = tspan[b];
  float acc = 0.f;
  for (int k = 0; k < 256; ++k)
    acc += alpha[b * 256 + k] * A[k * HID + h] - ts * beta[b * 256 + k] * Bm[k * HID + h];
  for (int k = 0; k < 16; ++k)
    acc += theta[b * 16 + k] * C[k * HID + h];
  mdhp[idx] = tanhf(acc);
}

// ---- the persistent recurrence kernel --------------------------------------
__global__ __launch_bounds__(256, 1) void lstm_persist(
    const short* __restrict__ xb, const float* __restrict__ c0,
    const float* __restrict__ bi, const float* __restrict__ bf_,
    const float* __restrict__ bc, const float* __restrict__ bo,
    const float* __restrict__ Wi, const float* __restrict__ Ui,
    const float* __restrict__ Wf, const float* __restrict__ Uf,
    const float* __restrict__ Wc, const float* __restrict__ Uc,
    const float* __restrict__ Wo, const float* __restrict__ Uo,
    const float* __restrict__ mdhp,
    short* hbuf, float* out) {
  __shared__ __align__(16) short Bs[64 * BS_STRIDE];   // 99,328 B
  __shared__ float gbuf[2][4][16][17];                 // parity dbuf: 8,704 B

  const int tid = threadIdx.x;
  const int wg = blockIdx.x;
  const int chain = wg & 7;
  const int j = wg >> 3;           // 0..31 column group

  // stage B^T slice straight from fp32 W/U (r6/r7-proven): row lr = g*16+c
  // holds bf16 of (k<256 ? W_g[k][hc] : U_g[k-256][hc]), hc = j*16+c.
  for (int g = 0; g < 4; ++g) {
    const float* W = (g == 0) ? Wi : (g == 1) ? Wf : (g == 2) ? Wc : Wo;
    const float* U = (g == 0) ? Ui : (g == 1) ? Uf : (g == 2) ? Uc : Uo;
    for (int it = tid; it < 16 * KTOT; it += 256) {
      int c = it & 15;                      // lane-consecutive -> coalesced hc
      int k = it >> 4;
      int hc = (j << 4) + c;
      float v = (k < DIN) ? W[k * HID + hc] : U[(k - DIN) * HID + hc];
      Bs[(g * 16 + c) * BS_STRIDE + k] = f2bf(v);
    }
  }

  // per-thread epilogue state in registers
  const int er = tid >> 4, ec = tid & 15;
  const int brow = (chain << 4) + er, hcol = (j << 4) + ec;
  float creg = c0[brow * HID + hcol];
  const float mdv = mdhp[brow * HID + hcol];
  const float b0 = bi[hcol], b1 = bf_[hcol], b2 = bc[hcol], b3 = bo[hcol];

  __syncthreads();                          // covers Bs staging

  const int lane = tid & 63;
  const int g = tid >> 6;                 // wave = gate
  const int mr = lane & 15;               // A-row / B-col within tile
  const int q = lane >> 4;                // quad
  const int bglob = (chain << 4) + mr;
  const short* Brow = &Bs[(g * 16 + mr) * BS_STRIDE + q * 8];

  for (int t = 0; t < SEQ; ++t) {
    // ---- issue x A-frag loads (h-independent; in flight across the poll)
    const short* xr = xb + ((size_t)t * BATCH + bglob) * DIN + q * 8;
    short8 xaf[8];
#pragma unroll
    for (int kk = 0; kk < 8; ++kk) xaf[kk] = *(const short8*)(xr + kk * 32);

    // ---- acquire h_{t-1} (slot t): data-as-flag with fenced retry ---------
    const short* hr = hbuf + ((size_t)t * BATCH + bglob) * HID + q * 8;
    short8 haf[16];
    {
      int att = 0;
      for (;;) {
        if (att <= 64) {
          // plain vectorized loads: fresh addr (t-indexed) -> L1-cold on
          // first attempt; after the fence, retries re-fetch from IF.
#pragma unroll
          for (int kk = 0; kk < 16; ++kk)
            haf[kk] = *(const short8*)(hr + kk * 32);
        } else {
          // bedrock escape: per-dword AGENT atomic loads (cache-proof).
          const unsigned* hd = (const unsigned*)hr;
#pragma unroll
          for (int kk = 0; kk < 16; ++kk) {
            unsigned w[4];
#pragma unroll
            for (int d = 0; d < 4; ++d)
              w[d] = __hip_atomic_load(hd + kk * 16 + d, __ATOMIC_RELAXED,
                                       __HIP_MEMORY_SCOPE_AGENT);
            __builtin_memcpy(&haf[kk], w, 16);
          }
        }
        if (!__any(nan_max(haf) == 0xFFFFFFFFu)) break;
        ++att;
        // acquire-agent fence: s_waitcnt + cache invalidate -> retry is
        // coherent with remote agent stores (the r4 missing piece).
        __builtin_amdgcn_fence(__ATOMIC_ACQUIRE, "agent");
        if (att > 4) __builtin_amdgcn_s_sleep(1);
      }
    }
    __builtin_amdgcn_sched_barrier(0);

    floatx4 ax  = {0.f, 0.f, 0.f, 0.f};
    floatx4 ah0 = {0.f, 0.f, 0.f, 0.f};
    floatx4 ah1 = {0.f, 0.f, 0.f, 0.f};

    // ---- x @ W MFMAs
#pragma unroll
    for (int kk = 0; kk < 8; ++kk)
      ax = __builtin_amdgcn_mfma_f32_16x16x32_bf16(
          xaf[kk], *(const short8*)(Brow + kk * 32), ax, 0, 0, 0);

    // ---- h @ U MFMAs, two independent chains for latency
#pragma unroll
    for (int kk = 0; kk < 8; ++kk) {
      ah0 = __builtin_amdgcn_mfma_f32_16x16x32_bf16(
          haf[kk], *(const short8*)(Brow + DIN + kk * 32), ah0, 0, 0, 0);
      ah1 = __builtin_amdgcn_mfma_f32_16x16x32_bf16(
          haf[8 + kk], *(const short8*)(Brow + DIN + (8 + kk) * 32), ah1, 0, 0, 0);
    }

    // ---- epilogue: C/D layout col=lane&15, row=q*4+i (m89); gbuf parity
    const int p = t & 1;
#pragma unroll
    for (int i = 0; i < 4; ++i)
      gbuf[p][g][q * 4 + i][mr] = ax[i] + ah0[i] + ah1[i];
    __syncthreads();                         // the ONE barrier per step
    {
      float gi = gbuf[p][0][er][ec] + b0;
      float gf = gbuf[p][1][er][ec] + b1;
      float gc = gbuf[p][2][er][ec] + b2;
      float go = gbuf[p][3][er][ec] + b3;
      float it = fsig(gi), ft = fsig(gf), ot = fsig(go);
      float ch = ftanh(gc);
      float cn = mdv * (ft * creg + it * ch);
      creg = cn;
      float hv = ot * ftanh(cn);

      if (t < SEQ - 1) {
        // bf16 h store to slot t+1: pair lanes -> one agent 4B store
        // (write-through to IF; this IS the entire publish).
        unsigned hb = (unsigned)(unsigned short)f2bf(hv);
        unsigned other = (unsigned)__shfl_xor((int)hb, 1, 64);
        if ((tid & 1) == 0) {
          unsigned pack = hb | (other << 16);
          size_t hidx = ((size_t)(t + 1) * BATCH + brow) * HID + hcol; // ec even
          __hip_atomic_store((unsigned*)&hbuf[hidx], pack, __ATOMIC_RELAXED,
                             __HIP_MEMORY_SCOPE_AGENT);
        }
      }

      // fp32 output (not read by consumers)
      size_t oidx = ((size_t)t * BATCH + brow) * HID + hcol;
      out[oidx] = hv;
      if (t == SEQ - 1) {
        size_t base = (size_t)SEQ * BATCH * HID;
        int e = brow * HID + hcol;
        out[base + e] = hv;                    // h_T
        out[base + BATCH * HID + e] = cn;      // c_T
      }
    }
  }
}

// ---------------------------------------------------------------------------
extern "C" void kernel_launch(void* const* d_in, const int* in_sizes, int n_in,
                              void* d_out, int out_size, void* d_ws, size_t ws_size,
                              hipStream_t stream) {
  const float* x     = (const float*)d_in[0];
  const float* h0    = (const float*)d_in[1];
  const float* c0    = (const float*)d_in[2];
  const float* alpha = (const float*)d_in[3];
  const float* beta  = (const float*)d_in[4];
  const float* theta = (const float*)d_in[5];
  const float* tspan = (const float*)d_in[6];
  const float* Amd   = (const float*)d_in[7];
  const float* Bmd   = (const float*)d_in[8];
  const float* Cmd   = (const float*)d_in[9];
  const float* Wi = (const float*)d_in[10]; const float* Ui = (const float*)d_in[11];
  const float* bi = (const float*)d_in[12];
  const float* Wf = (const float*)d_in[13]; const float* Uf = (const float*)d_in[14];
  const float* bf_ = (const float*)d_in[15];
  const float* Wc = (const float*)d_in[16]; const float* Uc = (const float*)d_in[17];
  const float* bc = (const float*)d_in[18];
  const float* Wo = (const float*)d_in[19]; const float* Uo = (const float*)d_in[20];
  const float* bo = (const float*)d_in[21];

  float* out = (float*)d_out;
  char* ws = (char*)d_ws;
  // ws layout (bytes):
  float* mdhp = (float*)ws;                           // @0              262,144
  short* xb   = (short*)(ws + 262144);                // @262,144     33,554,432
  short* hbuf = (short*)(ws + 33816576);              // @33,816,576  67,108,864
  // total: 100,925,440 B  (3.3 MB under the proven 104.2 MB ceiling)

  prep_xb<<<16384, 256, 0, stream>>>(x, xb);
  fill_nan<<<16384, 256, 0, stream>>>((uint4*)hbuf);
  prep_h0<<<256, 256, 0, stream>>>(h0, hbuf);         // after fill_nan
  prep_mdhp<<<256, 256, 0, stream>>>(alpha, beta, theta, tspan, Amd, Bmd, Cmd, mdhp);
  lstm_persist<<<NCHAIN * NCOLW, 256, 0, stream>>>(
      xb, c0, bi, bf_, bc, bo, Wi, Ui, Wf, Uf, Wc, Uc, Wo, Uo,
      mdhp, hbuf, out);
}

// Round 9
// 4100.631 us; speedup vs baseline: 2.9691x; 1.2112x over previous
//
#include <hip/hip_runtime.h>
#include <cstdint>
#include <cstddef>

// ---------------------------------------------------------------------------
// MDHP-LSTM on MI355X.  S=512, B=128, D=256, H=512.
// Round-11: r0 skeleton, RMW-free publish.  Transport taxonomy (r0-r8):
//   r0 tid0-RMW-counter 3.93us/step (best) | r3 L2-atomic flags 4.3 |
//   r4 data-poll 4.15+pathology | r6/r7 load-polled sentinel ~13 (all-wave
//   congestion) | r8 fence-retry 9.4 (cache-inv thrash, FETCH x3.4).
// The only untested combo of PROVEN primitives:
//   * publish: per-WG byte sentinel, PARALLEL agent stores (no 32-way RMW
//     serialization at the IF) -- byte-store+agent-load transport proven r7.
//   * poll: tid0 ONLY (r0-proven discipline), batched 4x8B agent atomic
//     loads (one IF trip/attempt), barrier fanout. 32 pollers/chain, not 128.
//   * h channel: agent stores -> plain fresh-address loads (r0-proven).
//   * out stores moved AFTER publish: their drain leaves the critical path.
//   * sentinel slots 64B apart: no line sharing between steps.
// ---------------------------------------------------------------------------

typedef __attribute__((ext_vector_type(8))) short short8;
typedef __attribute__((ext_vector_type(4))) float floatx4;

#define SEQ 512
#define BATCH 128
#define DIN 256
#define HID 512
#define KTOT 768
#define NCHAIN 8
#define NCOLW 32
#define BS_STRIDE 776         // shorts per LDS B-row (768 + 8 pad, 16B aligned)

__device__ __forceinline__ short f2bf(float f) {
  union { float f; unsigned u; } v; v.f = f;
  unsigned u = v.u + 0x7fffu + ((v.u >> 16) & 1u);   // RNE
  return (short)(u >> 16);
}
__device__ __forceinline__ float fsig(float x) {
  return 1.f / (1.f + __expf(-x));
}
__device__ __forceinline__ float ftanh(float x) {
  float a = fabsf(x);
  float e = __expf(-2.f * a);
  float r = (1.f - e) / (1.f + e);
  return copysignf(r, x);
}

// ---- prep: x -> bf16 (4 elems/thread)
__global__ void prep_xb(const float* __restrict__ x, short* __restrict__ xb) {
  int idx = blockIdx.x * 256 + threadIdx.x;           // 4,194,304
  float4 v = ((const float4*)x)[idx];
  short4 o; o.x = f2bf(v.x); o.y = f2bf(v.y); o.z = f2bf(v.z); o.w = f2bf(v.w);
  ((short4*)xb)[idx] = o;
}

// ---- prep: h0 -> hbuf slot 0 (bf16)
__global__ void prep_h0(const float* __restrict__ h0, short* __restrict__ hbuf) {
  int idx = blockIdx.x * 256 + threadIdx.x;           // 65536
  hbuf[idx] = f2bf(h0[idx]);
}

// ---- prep: mdhp[b][h] = tanh(alpha@A - (beta*tspan)@B + theta@C)  (fp32)
__global__ void prep_mdhp(const float* __restrict__ alpha, const float* __restrict__ beta,
                          const float* __restrict__ theta, const float* __restrict__ tspan,
                          const float* __restrict__ A, const float* __restrict__ Bm,
                          const float* __restrict__ C, float* __restrict__ mdhp) {
  int idx = blockIdx.x * 256 + threadIdx.x;           // 65536
  int b = idx >> 9, h = idx & 511;
  float ts = tspan[b];
  float acc = 0.f;
  for (int k = 0; k < 256; ++k)
    acc += alpha[b * 256 + k] * A[k * HID + h] - ts * beta[b * 256 + k] * Bm[k * HID + h];
  for (int k = 0; k < 16; ++k)
    acc += theta[b * 16 + k] * C[k * HID + h];
  mdhp[idx] = tanhf(acc);
}

// ---- zero sentinel lines (must run every launch: graph replays)
__global__ void zero_sync(unsigned* __restrict__ sent32) {
  int idx = blockIdx.x * 256 + threadIdx.x;           // grid 256*256 = 65536
  sent32[idx] = 0;                                    // 262,144 B of sentinels
}

// ---- the persistent recurrence kernel --------------------------------------
__global__ __launch_bounds__(256, 1) void lstm_persist(
    const short* __restrict__ xb, const float* __restrict__ c0,
    const float* __restrict__ bi, const float* __restrict__ bf_,
    const float* __restrict__ bc, const float* __restrict__ bo,
    const float* __restrict__ Wi, const float* __restrict__ Ui,
    const float* __restrict__ Wf, const float* __restrict__ Uf,
    const float* __restrict__ Wc, const float* __restrict__ Uc,
    const float* __restrict__ Wo, const float* __restrict__ Uo,
    const float* __restrict__ mdhp,
    unsigned char* sent, short* hbuf, float* out) {
  __shared__ __align__(16) short Bs[64 * BS_STRIDE];   // 99,328 B
  __shared__ float gbuf[2][4][16][17];                 // parity dbuf: 8,704 B
  __shared__ int wv[SEQ];                              // per-step wave counter

  const int tid = threadIdx.x;
  const int wg = blockIdx.x;
  const int chain = wg & 7;
  const int j = wg >> 3;           // 0..31 column group

  // stage B^T slice straight from fp32 W/U (r6-r8 proven): row lr = g*16+c
  // holds bf16 of (k<256 ? W_g[k][hc] : U_g[k-256][hc]), hc = j*16+c.
  for (int g = 0; g < 4; ++g) {
    const float* W = (g == 0) ? Wi : (g == 1) ? Wf : (g == 2) ? Wc : Wo;
    const float* U = (g == 0) ? Ui : (g == 1) ? Uf : (g == 2) ? Uc : Uo;
    for (int it = tid; it < 16 * KTOT; it += 256) {
      int c = it & 15;                      // lane-consecutive -> coalesced hc
      int k = it >> 4;
      int hc = (j << 4) + c;
      float v = (k < DIN) ? W[k * HID + hc] : U[(k - DIN) * HID + hc];
      Bs[(g * 16 + c) * BS_STRIDE + k] = f2bf(v);
    }
  }
  for (int i = tid; i < SEQ; i += 256) wv[i] = 0;

  // per-thread epilogue state in registers
  const int er = tid >> 4, ec = tid & 15;
  const int brow = (chain << 4) + er, hcol = (j << 4) + ec;
  float creg = c0[brow * HID + hcol];
  const float mdv = mdhp[brow * HID + hcol];
  const float b0 = bi[hcol], b1 = bf_[hcol], b2 = bc[hcol], b3 = bo[hcol];

  __syncthreads();                          // covers Bs / wv staging

  const int lane = tid & 63;
  const int g = tid >> 6;                 // wave = gate
  const int mr = lane & 15;               // A-row / B-col within tile
  const int q = lane >> 4;                // quad
  const int bglob = (chain << 4) + mr;
  const short* Brow = &Bs[(g * 16 + mr) * BS_STRIDE + q * 8];

  for (int t = 0; t < SEQ; ++t) {
    // ---- issue x A-frag loads (h-independent; in flight across the poll)
    const short* xr = xb + ((size_t)t * BATCH + bglob) * DIN + q * 8;
    short8 xaf[8];
#pragma unroll
    for (int kk = 0; kk < 8; ++kk) xaf[kk] = *(const short8*)(xr + kk * 32);

    // ---- wait for h_{t-1}: tid0 polls 32 sentinel bytes (4x8B agent loads,
    //      one IF trip per attempt); barrier fans the release out (r0 style).
    if (t > 0) {
      if (tid == 0) {
        const unsigned long long* sp = (const unsigned long long*)
            (sent + ((size_t)(chain * SEQ + t) << 6));
        int att = 0;
        for (;;) {
          unsigned long long a = __hip_atomic_load(&sp[0], __ATOMIC_RELAXED,
                                                   __HIP_MEMORY_SCOPE_AGENT);
          unsigned long long b = __hip_atomic_load(&sp[1], __ATOMIC_RELAXED,
                                                   __HIP_MEMORY_SCOPE_AGENT);
          unsigned long long c = __hip_atomic_load(&sp[2], __ATOMIC_RELAXED,
                                                   __HIP_MEMORY_SCOPE_AGENT);
          unsigned long long d = __hip_atomic_load(&sp[3], __ATOMIC_RELAXED,
                                                   __HIP_MEMORY_SCOPE_AGENT);
          if ((a & b & c & d) == 0x0101010101010101ull) break;
          if (++att > 2) __builtin_amdgcn_s_sleep(1);
        }
        // acquire: orders the workgroup's h loads after the observation
        (void)__hip_atomic_load(&sp[0], __ATOMIC_ACQUIRE,
                                __HIP_MEMORY_SCOPE_AGENT);
      }
      __syncthreads();
    }

    // ---- h A-frag loads, ONCE, plain (fresh t-indexed addr -> L1 miss ->
    //      L2/IF serves the agent-stored data; r0-proven channel)
    const short* hr = hbuf + ((size_t)t * BATCH + bglob) * HID + q * 8;
    short8 haf[16];
#pragma unroll
    for (int kk = 0; kk < 16; ++kk) haf[kk] = *(const short8*)(hr + kk * 32);

    floatx4 ax  = {0.f, 0.f, 0.f, 0.f};
    floatx4 ah0 = {0.f, 0.f, 0.f, 0.f};
    floatx4 ah1 = {0.f, 0.f, 0.f, 0.f};

    // ---- x @ W MFMAs (overlap h-load latency)
#pragma unroll
    for (int kk = 0; kk < 8; ++kk)
      ax = __builtin_amdgcn_mfma_f32_16x16x32_bf16(
          xaf[kk], *(const short8*)(Brow + kk * 32), ax, 0, 0, 0);

    // ---- h @ U MFMAs, two independent chains for latency
#pragma unroll
    for (int kk = 0; kk < 8; ++kk) {
      ah0 = __builtin_amdgcn_mfma_f32_16x16x32_bf16(
          haf[kk], *(const short8*)(Brow + DIN + kk * 32), ah0, 0, 0, 0);
      ah1 = __builtin_amdgcn_mfma_f32_16x16x32_bf16(
          haf[8 + kk], *(const short8*)(Brow + DIN + (8 + kk) * 32), ah1, 0, 0, 0);
    }

    // ---- epilogue: C/D layout col=lane&15, row=q*4+i (m89); gbuf parity
    const int p = t & 1;
#pragma unroll
    for (int i = 0; i < 4; ++i)
      gbuf[p][g][q * 4 + i][mr] = ax[i] + ah0[i] + ah1[i];
    __syncthreads();                         // epilogue barrier
    {
      float gi = gbuf[p][0][er][ec] + b0;
      float gf = gbuf[p][1][er][ec] + b1;
      float gc = gbuf[p][2][er][ec] + b2;
      float go = gbuf[p][3][er][ec] + b3;
      float it = fsig(gi), ft = fsig(gf), ot = fsig(go);
      float ch = ftanh(gc);
      float cn = mdv * (ft * creg + it * ch);
      creg = cn;
      float hv = ot * ftanh(cn);

      if (t < SEQ - 1) {
        // bf16 h store to slot t+1: pair lanes -> one agent 4B store
        unsigned hb = (unsigned)(unsigned short)f2bf(hv);
        unsigned other = (unsigned)__shfl_xor((int)hb, 1, 64);
        if ((tid & 1) == 0) {
          unsigned pack = hb | (other << 16);
          size_t hidx = ((size_t)(t + 1) * BATCH + brow) * HID + hcol; // ec even
          __hip_atomic_store((unsigned*)&hbuf[hidx], pack, __ATOMIC_RELAXED,
                             __HIP_MEMORY_SCOPE_AGENT);
        }
        // publish: h acked -> LDS wave count -> last wave writes its byte
        // sentinel (PARALLEL across the 32 WGs: no same-address RMW at IF)
        asm volatile("s_waitcnt vmcnt(0)" ::: "memory");
        if (lane == 0) {
          int old = __hip_atomic_fetch_add(&wv[t], 1, __ATOMIC_RELAXED,
                                           __HIP_MEMORY_SCOPE_WORKGROUP);
          if (old == 3) {                       // all 4 waves' h committed
            __hip_atomic_store(
                sent + ((size_t)(chain * SEQ + t + 1) << 6) + j,
                (unsigned char)1, __ATOMIC_RELAXED, __HIP_MEMORY_SCOPE_AGENT);
          }
        }
      }

      // fp32 out stores AFTER the publish: their drain is off-path, they
      // complete under the next step's poll.
      size_t oidx = ((size_t)t * BATCH + brow) * HID + hcol;
      out[oidx] = hv;
      if (t == SEQ - 1) {
        size_t base = (size_t)SEQ * BATCH * HID;
        int e = brow * HID + hcol;
        out[base + e] = hv;                    // h_T
        out[base + BATCH * HID + e] = cn;      // c_T
      }
    }
  }
}

// ---------------------------------------------------------------------------
extern "C" void kernel_launch(void* const* d_in, const int* in_sizes, int n_in,
                              void* d_out, int out_size, void* d_ws, size_t ws_size,
                              hipStream_t stream) {
  const float* x     = (const float*)d_in[0];
  const float* h0    = (const float*)d_in[1];
  const float* c0    = (const float*)d_in[2];
  const float* alpha = (const float*)d_in[3];
  const float* beta  = (const float*)d_in[4];
  const float* theta = (const float*)d_in[5];
  const float* tspan = (const float*)d_in[6];
  const float* Amd   = (const float*)d_in[7];
  const float* Bmd   = (const float*)d_in[8];
  const float* Cmd   = (const float*)d_in[9];
  const float* Wi = (const float*)d_in[10]; const float* Ui = (const float*)d_in[11];
  const float* bi = (const float*)d_in[12];
  const float* Wf = (const float*)d_in[13]; const float* Uf = (const float*)d_in[14];
  const float* bf_ = (const float*)d_in[15];
  const float* Wc = (const float*)d_in[16]; const float* Uc = (const float*)d_in[17];
  const float* bc = (const float*)d_in[18];
  const float* Wo = (const float*)d_in[19]; const float* Uo = (const float*)d_in[20];
  const float* bo = (const float*)d_in[21];

  float* out = (float*)d_out;
  char* ws = (char*)d_ws;
  // ws layout (bytes):
  float* mdhp        = (float*)ws;                    // @0              262,144
  unsigned char* sent= (unsigned char*)(ws + 262144); // @262,144        262,144
  short* xb          = (short*)(ws + 524288);         // @524,288     33,554,432
  short* hbuf        = (short*)(ws + 34078720);       // @34,078,720  67,108,864
  // total: 101,187,584 B  (3.0 MB under the proven 104.2 MB ceiling)

  zero_sync<<<256, 256, 0, stream>>>((unsigned*)sent);
  prep_xb<<<16384, 256, 0, stream>>>(x, xb);
  prep_h0<<<256, 256, 0, stream>>>(h0, hbuf);
  prep_mdhp<<<256, 256, 0, stream>>>(alpha, beta, theta, tspan, Amd, Bmd, Cmd, mdhp);
  lstm_persist<<<NCHAIN * NCOLW, 256, 0, stream>>>(
      xb, c0, bi, bf_, bc, bo, Wi, Ui, Wf, Uf, Wc, Uc, Wo, Uo,
      mdhp, sent, hbuf, out);
}

// Round 10
// 2593.548 us; speedup vs baseline: 4.6945x; 1.5811x over previous
//
#include <hip/hip_runtime.h>
#include <cstdint>
#include <cstddef>

// ---------------------------------------------------------------------------
// MDHP-LSTM on MI355X.  S=512, B=128, D=256, H=512.
// Round-12: ZERO-FLAG data-observation transport via sc0 sc1 (IF-direct).
// Taxonomy (step time): r0 tid0-RMW 3.93us | r3 asm-RMW 4.3 | r4 data-poll
// sc0 4.15+stale-L1 pathology | r6/r7 load-polled flags ~13 | r8 fence 9.4 |
// r9 byte-sentinel 7.65 (byte stores serialize at IF).  Flag floor ~4us =
// ack + inc-convoy + observe + fetch, serialized at the IF.
// This round: hbuf NaN-prefilled; producers agent-store packed h dwords and
// NOTHING else on the critical path; consumers re-read their OWN h tile with
// sc0 sc1 loads (bypass L1+L2 -> IF: same-address retry CANNOT be stale,
// the r4 killer is structurally absent) until no 0xFFFFFFFF word remains.
// No ack, no publish, no flag, no fanout in the steady state.
// Insurance (off-path): one fire-and-forget RMW inc per WG/step; consumers
// stuck >30k attempts wait on the counter, then resume data-polling.
// ---------------------------------------------------------------------------

typedef __attribute__((ext_vector_type(8))) short short8;
typedef __attribute__((ext_vector_type(4))) float floatx4;

#define SEQ 512
#define BATCH 128
#define DIN 256
#define HID 512
#define KTOT 768
#define NCHAIN 8
#define NCOLW 32
#define BS_STRIDE 776         // shorts per LDS B-row (768 + 8 pad, 16B aligned)

__device__ __forceinline__ short f2bf(float f) {
  union { float f; unsigned u; } v; v.f = f;
  unsigned u = v.u + 0x7fffu + ((v.u >> 16) & 1u);   // RNE
  return (short)(u >> 16);
}
__device__ __forceinline__ float fsig(float x) {
  return 1.f / (1.f + __expf(-x));
}
__device__ __forceinline__ float ftanh(float x) {
  float a = fabsf(x);
  float e = __expf(-2.f * a);
  float r = (1.f - e) / (1.f + e);
  return copysignf(r, x);
}
__device__ __forceinline__ unsigned umax2(unsigned a, unsigned b) {
  return a > b ? a : b;
}
// == 0xFFFFFFFF iff any dword is still the prefill sentinel.  Real packed
// bf16 h pairs are <= 0xBFxxBFxx (|h| <= 1) -> unreachable.
__device__ __forceinline__ unsigned nan_max(const short8 (&haf)[16]) {
  unsigned m = 0;
#pragma unroll
  for (int kk = 0; kk < 16; ++kk) {
    unsigned w[4];
    __builtin_memcpy(w, &haf[kk], 16);
    m = umax2(m, umax2(umax2(w[0], w[1]), umax2(w[2], w[3])));
  }
  return m;
}
// 16 A-frag loads, IF-coherent (sc0 sc1: bypass L1 AND L2), one vmcnt(0).
// Early-clobber outputs (r5 lesson: cannot alias the address pair).
__device__ __forceinline__ void hload16_if(const short* hr, short8 (&haf)[16]) {
  asm volatile(
      "global_load_dwordx4 %0,  %16, off sc0 sc1\n\t"
      "global_load_dwordx4 %1,  %16, off offset:64 sc0 sc1\n\t"
      "global_load_dwordx4 %2,  %16, off offset:128 sc0 sc1\n\t"
      "global_load_dwordx4 %3,  %16, off offset:192 sc0 sc1\n\t"
      "global_load_dwordx4 %4,  %16, off offset:256 sc0 sc1\n\t"
      "global_load_dwordx4 %5,  %16, off offset:320 sc0 sc1\n\t"
      "global_load_dwordx4 %6,  %16, off offset:384 sc0 sc1\n\t"
      "global_load_dwordx4 %7,  %16, off offset:448 sc0 sc1\n\t"
      "global_load_dwordx4 %8,  %16, off offset:512 sc0 sc1\n\t"
      "global_load_dwordx4 %9,  %16, off offset:576 sc0 sc1\n\t"
      "global_load_dwordx4 %10, %16, off offset:640 sc0 sc1\n\t"
      "global_load_dwordx4 %11, %16, off offset:704 sc0 sc1\n\t"
      "global_load_dwordx4 %12, %16, off offset:768 sc0 sc1\n\t"
      "global_load_dwordx4 %13, %16, off offset:832 sc0 sc1\n\t"
      "global_load_dwordx4 %14, %16, off offset:896 sc0 sc1\n\t"
      "global_load_dwordx4 %15, %16, off offset:960 sc0 sc1\n\t"
      "s_waitcnt vmcnt(0)"
      : "=&v"(haf[0]), "=&v"(haf[1]), "=&v"(haf[2]), "=&v"(haf[3]),
        "=&v"(haf[4]), "=&v"(haf[5]), "=&v"(haf[6]), "=&v"(haf[7]),
        "=&v"(haf[8]), "=&v"(haf[9]), "=&v"(haf[10]), "=&v"(haf[11]),
        "=&v"(haf[12]), "=&v"(haf[13]), "=&v"(haf[14]), "=&v"(haf[15])
      : "v"((unsigned long long)(uintptr_t)hr)
      : "memory");
}

// ---- prep: x -> bf16 (4 elems/thread)
__global__ void prep_xb(const float* __restrict__ x, short* __restrict__ xb) {
  int idx = blockIdx.x * 256 + threadIdx.x;           // 4,194,304
  float4 v = ((const float4*)x)[idx];
  short4 o; o.x = f2bf(v.x); o.y = f2bf(v.y); o.z = f2bf(v.z); o.w = f2bf(v.w);
  ((short4*)xb)[idx] = o;
}

// ---- prep: fill hbuf with NaN sentinel (must run EVERY launch: graph replay)
__global__ void fill_nan(uint4* __restrict__ hb) {
  int idx = blockIdx.x * 256 + threadIdx.x;           // 4,194,304
  uint4 v; v.x = 0xFFFFFFFFu; v.y = 0xFFFFFFFFu; v.z = 0xFFFFFFFFu; v.w = 0xFFFFFFFFu;
  hb[idx] = v;
}

// ---- prep: h0 -> hbuf slot 0 (bf16); AFTER fill_nan in stream order
__global__ void prep_h0(const float* __restrict__ h0, short* __restrict__ hbuf) {
  int idx = blockIdx.x * 256 + threadIdx.x;           // 65536
  hbuf[idx] = f2bf(h0[idx]);
}

// ---- prep: mdhp[b][h] = tanh(alpha@A - (beta*tspan)@B + theta@C)  (fp32)
__global__ void prep_mdhp(const float* __restrict__ alpha, const float* __restrict__ beta,
                          const float* __restrict__ theta, const float* __restrict__ tspan,
                          const float* __restrict__ A, const float* __restrict__ Bm,
                          const float* __restrict__ C, float* __restrict__ mdhp) {
  int idx = blockIdx.x * 256 + threadIdx.x;           // 65536
  int b = idx >> 9, h = idx & 511;
  float ts = tspan[b];
  float acc = 0.f;
  for (int k = 0; k < 256; ++k)
    acc += alpha[b * 256 + k] * A[k * HID + h] - ts * beta[b * 256 + k] * Bm[k * HID + h];
  for (int k = 0; k < 16; ++k)
    acc += theta[b * 16 + k] * C[k * HID + h];
  mdhp[idx] = tanhf(acc);
}

// ---- zero insurance counters (every launch)
__global__ void zero_sync(int* __restrict__ cnt) {
  int idx = blockIdx.x * 256 + threadIdx.x;           // 16*256 = 4096
  if (idx < NCHAIN * SEQ) cnt[idx] = 0;
}

// ---- the persistent recurrence kernel --------------------------------------
__global__ __launch_bounds__(256, 1) void lstm_persist(
    const short* __restrict__ xb, const float* __restrict__ c0,
    const float* __restrict__ bi, const float* __restrict__ bf_,
    const float* __restrict__ bc, const float* __restrict__ bo,
    const float* __restrict__ Wi, const float* __restrict__ Ui,
    const float* __restrict__ Wf, const float* __restrict__ Uf,
    const float* __restrict__ Wc, const float* __restrict__ Uc,
    const float* __restrict__ Wo, const float* __restrict__ Uo,
    const float* __restrict__ mdhp,
    int* cnt, short* hbuf, float* out) {
  __shared__ __align__(16) short Bs[64 * BS_STRIDE];   // 99,328 B
  __shared__ float gbuf[2][4][16][17];                 // parity dbuf: 8,704 B

  const int tid = threadIdx.x;
  const int wg = blockIdx.x;
  const int chain = wg & 7;
  const int j = wg >> 3;           // 0..31 column group

  // stage B^T slice straight from fp32 W/U (r6-r9 proven): row lr = g*16+c
  // holds bf16 of (k<256 ? W_g[k][hc] : U_g[k-256][hc]), hc = j*16+c.
  for (int g = 0; g < 4; ++g) {
    const float* W = (g == 0) ? Wi : (g == 1) ? Wf : (g == 2) ? Wc : Wo;
    const float* U = (g == 0) ? Ui : (g == 1) ? Uf : (g == 2) ? Uc : Uo;
    for (int it = tid; it < 16 * KTOT; it += 256) {
      int c = it & 15;                      // lane-consecutive -> coalesced hc
      int k = it >> 4;
      int hc = (j << 4) + c;
      float v = (k < DIN) ? W[k * HID + hc] : U[(k - DIN) * HID + hc];
      Bs[(g * 16 + c) * BS_STRIDE + k] = f2bf(v);
    }
  }

  // per-thread epilogue state in registers
  const int er = tid >> 4, ec = tid & 15;
  const int brow = (chain << 4) + er, hcol = (j << 4) + ec;
  float creg = c0[brow * HID + hcol];
  const float mdv = mdhp[brow * HID + hcol];
  const float b0 = bi[hcol], b1 = bf_[hcol], b2 = bc[hcol], b3 = bo[hcol];

  __syncthreads();                          // covers Bs staging

  const int lane = tid & 63;
  const int g = tid >> 6;                 // wave = gate
  const int mr = lane & 15;               // A-row / B-col within tile
  const int q = lane >> 4;                // quad
  const int bglob = (chain << 4) + mr;
  const short* Brow = &Bs[(g * 16 + mr) * BS_STRIDE + q * 8];
  int* mycnt = cnt + chain * SEQ;

  for (int t = 0; t < SEQ; ++t) {
    // ---- issue x A-frag loads (h-independent; drain at the poll's vmcnt)
    const short* xr = xb + ((size_t)t * BATCH + bglob) * DIN + q * 8;
    short8 xaf[8];
#pragma unroll
    for (int kk = 0; kk < 8; ++kk) xaf[kk] = *(const short8*)(xr + kk * 32);

    // ---- acquire h_{t-1} (slot t) by OBSERVING THE DATA: sc0 sc1 loads
    //      read the IF directly (no L1/L2 staleness possible).
    const short* hr = hbuf + ((size_t)t * BATCH + bglob) * HID + q * 8;
    short8 haf[16];
    {
      int att = 0;
      for (;;) {
        hload16_if(hr, haf);
        if (!__any(nan_max(haf) == 0xFFFFFFFFu)) break;
        ++att;
        if (att > 30000 && t > 0) {
          // insurance: wait until all 32 producer WGs have signalled, then
          // keep re-loading (monotonic; converges within a trip or two).
          while (__hip_atomic_load(&mycnt[t - 1], __ATOMIC_RELAXED,
                                   __HIP_MEMORY_SCOPE_AGENT) < NCOLW)
            __builtin_amdgcn_s_sleep(8);
          att = 20000;                      // re-check data, re-arm slowly
        } else if (att > 3) {
          __builtin_amdgcn_s_sleep(1);      // backoff caps IF read traffic
        }
      }
    }
    __builtin_amdgcn_sched_barrier(0);      // rule 18: pin MFMAs after vmcnt

    floatx4 ax  = {0.f, 0.f, 0.f, 0.f};
    floatx4 ah0 = {0.f, 0.f, 0.f, 0.f};
    floatx4 ah1 = {0.f, 0.f, 0.f, 0.f};

    // ---- x @ W MFMAs
#pragma unroll
    for (int kk = 0; kk < 8; ++kk)
      ax = __builtin_amdgcn_mfma_f32_16x16x32_bf16(
          xaf[kk], *(const short8*)(Brow + kk * 32), ax, 0, 0, 0);

    // ---- h @ U MFMAs, two independent chains for latency
#pragma unroll
    for (int kk = 0; kk < 8; ++kk) {
      ah0 = __builtin_amdgcn_mfma_f32_16x16x32_bf16(
          haf[kk], *(const short8*)(Brow + DIN + kk * 32), ah0, 0, 0, 0);
      ah1 = __builtin_amdgcn_mfma_f32_16x16x32_bf16(
          haf[8 + kk], *(const short8*)(Brow + DIN + (8 + kk) * 32), ah1, 0, 0, 0);
    }

    // ---- epilogue: C/D layout col=lane&15, row=q*4+i (m89); gbuf parity
    const int p = t & 1;
#pragma unroll
    for (int i = 0; i < 4; ++i)
      gbuf[p][g][q * 4 + i][mr] = ax[i] + ah0[i] + ah1[i];
    __syncthreads();                         // the ONE barrier per step
    {
      float gi = gbuf[p][0][er][ec] + b0;
      float gf = gbuf[p][1][er][ec] + b1;
      float gc = gbuf[p][2][er][ec] + b2;
      float go = gbuf[p][3][er][ec] + b3;
      float it = fsig(gi), ft = fsig(gf), ot = fsig(go);
      float ch = ftanh(gc);
      float cn = mdv * (ft * creg + it * ch);
      creg = cn;
      float hv = ot * ftanh(cn);

      if (t < SEQ - 1) {
        // THE publish: agent store of the packed dword (write-through to IF).
        unsigned hb = (unsigned)(unsigned short)f2bf(hv);
        unsigned other = (unsigned)__shfl_xor((int)hb, 1, 64);
        if ((tid & 1) == 0) {
          unsigned pack = hb | (other << 16);
          size_t hidx = ((size_t)(t + 1) * BATCH + brow) * HID + hcol; // ec even
          __hip_atomic_store((unsigned*)&hbuf[hidx], pack, __ATOMIC_RELAXED,
                             __HIP_MEMORY_SCOPE_AGENT);
        }
        // insurance inc: fire-and-forget, one per WG, off the critical path
        if (tid == 192)
          __hip_atomic_fetch_add(&mycnt[t], 1, __ATOMIC_RELAXED,
                                 __HIP_MEMORY_SCOPE_AGENT);
      }

      // fp32 out stores (never read by consumers; fully off-path)
      size_t oidx = ((size_t)t * BATCH + brow) * HID + hcol;
      out[oidx] = hv;
      if (t == SEQ - 1) {
        size_t base = (size_t)SEQ * BATCH * HID;
        int e = brow * HID + hcol;
        out[base + e] = hv;                    // h_T
        out[base + BATCH * HID + e] = cn;      // c_T
      }
    }
  }
}

// ---------------------------------------------------------------------------
extern "C" void kernel_launch(void* const* d_in, const int* in_sizes, int n_in,
                              void* d_out, int out_size, void* d_ws, size_t ws_size,
                              hipStream_t stream) {
  const float* x     = (const float*)d_in[0];
  const float* h0    = (const float*)d_in[1];
  const float* c0    = (const float*)d_in[2];
  const float* alpha = (const float*)d_in[3];
  const float* beta  = (const float*)d_in[4];
  const float* theta = (const float*)d_in[5];
  const float* tspan = (const float*)d_in[6];
  const float* Amd   = (const float*)d_in[7];
  const float* Bmd   = (const float*)d_in[8];
  const float* Cmd   = (const float*)d_in[9];
  const float* Wi = (const float*)d_in[10]; const float* Ui = (const float*)d_in[11];
  const float* bi = (const float*)d_in[12];
  const float* Wf = (const float*)d_in[13]; const float* Uf = (const float*)d_in[14];
  const float* bf_ = (const float*)d_in[15];
  const float* Wc = (const float*)d_in[16]; const float* Uc = (const float*)d_in[17];
  const float* bc = (const float*)d_in[18];
  const float* Wo = (const float*)d_in[19]; const float* Uo = (const float*)d_in[20];
  const float* bo = (const float*)d_in[21];

  float* out = (float*)d_out;
  char* ws = (char*)d_ws;
  // ws layout (bytes):
  float* mdhp = (float*)ws;                           // @0              262,144
  int*   cnt  = (int*)(ws + 262144);                  // @262,144         16,384
  short* xb   = (short*)(ws + 278528);                // @278,528     33,554,432
  short* hbuf = (short*)(ws + 33832960);              // @33,832,960  67,108,864
  // total: 100,941,824 B  (3.2 MB under the proven 104.2 MB ceiling)

  zero_sync<<<16, 256, 0, stream>>>(cnt);
  fill_nan<<<16384, 256, 0, stream>>>((uint4*)hbuf);
  prep_xb<<<16384, 256, 0, stream>>>(x, xb);
  prep_h0<<<256, 256, 0, stream>>>(h0, hbuf);         // after fill_nan
  prep_mdhp<<<256, 256, 0, stream>>>(alpha, beta, theta, tspan, Amd, Bmd, Cmd, mdhp);
  lstm_persist<<<NCHAIN * NCOLW, 256, 0, stream>>>(
      xb, c0, bi, bf_, bc, bo, Wi, Ui, Wf, Uf, Wc, Uc, Wo, Uo,
      mdhp, cnt, hbuf, out);
}